// Round 16
// baseline (70.684 us; speedup 1.0000x reference)
//
#include <hip/hip_runtime.h>
#include <hip/hip_bf16.h>
#include <stdint.h>

typedef __attribute__((ext_vector_type(8))) short bf16x8;
typedef __attribute__((ext_vector_type(4))) float f32x4;

__device__ __forceinline__ short f2bf(float x) {
    __hip_bfloat16 h = __float2bfloat16(x);   // native cvt on gfx950 (RNE)
    return __builtin_bit_cast(short, h);
}

__device__ __forceinline__ bf16x8 pack8(f32x4 a, f32x4 b) {
    bf16x8 r;
    r[0] = f2bf(a[0]); r[1] = f2bf(a[1]); r[2] = f2bf(a[2]); r[3] = f2bf(a[3]);
    r[4] = f2bf(b[0]); r[5] = f2bf(b[1]); r[6] = f2bf(b[2]); r[7] = f2bf(b[3]);
    return r;
}

// direct HBM->LDS DMA: 64 lanes x 16B, LDS dest = uniform base + lane*16
#define GLDS(gp, lp) __builtin_amdgcn_global_load_lds( \
    (const __attribute__((address_space(1))) void*)(gp), \
    (__attribute__((address_space(3))) void*)(lp), 16, 0, 0)

// ---------------------------------------------------------------------------
// Kernel C: repack Wq (1024x48 f32) into bf16 B-fragment layout.
// ---------------------------------------------------------------------------
__global__ __launch_bounds__(256) void prep_wfrag(const float* __restrict__ Wq,
                                                  short* __restrict__ wfrag) {
    int idx = blockIdx.x * 256 + threadIdx.x;   // 0..49151
    int j    = idx & 7;
    int lane = (idx >> 3) & 63;
    int grp  = idx >> 9;          // ks*3+nf
    int nf   = grp % 3;
    int ks   = grp / 3;
    int k = ks * 32 + ((lane >> 4) << 3) + j;
    int n = nf * 16 + (lane & 15);
    wfrag[idx] = f2bf(Wq[k * 48 + n]);
}

// ---------------------------------------------------------------------------
// Kernel A: qk = Q @ Wq + bq  (M=32768, N=48, K=1024), MFMA 16x16x32 bf16.
// Q loads are NON-TEMPORAL: Q has zero reuse, and streaming it through
// evict-first keeps K resident in the 256MB L3 for the conv kernel.
// Epilogue scatter-stores bf16 weights into A-frag layout:
//   wgtA[b][k][dg(128)][h(16)][8]
// ---------------------------------------------------------------------------
__global__ __launch_bounds__(256) void qk_gemm(const float* __restrict__ Q,
                                               const short* __restrict__ wfrag,
                                               const float* __restrict__ bq,
                                               short* __restrict__ wgtA) {
    const int l  = threadIdx.x & 63;
    const int w  = threadIdx.x >> 6;
    const int lr = l & 15;
    const int lk = l >> 4;
    const int row0 = blockIdx.x * 64 + w * 16;

    f32x4 acc[3];
    acc[0] = (f32x4){0.f, 0.f, 0.f, 0.f};
    acc[1] = acc[0];
    acc[2] = acc[0];

    const float* qbase = Q + (size_t)(row0 + lr) * 1024 + lk * 8;

    #pragma unroll 4
    for (int ks = 0; ks < 32; ++ks) {
        const float* p = qbase + ks * 32;
        f32x4 q0 = __builtin_nontemporal_load((const f32x4*)p);
        f32x4 q1 = __builtin_nontemporal_load((const f32x4*)(p + 4));
        bf16x8 a = pack8(q0, q1);
        const bf16x8* wp = (const bf16x8*)(wfrag + (size_t)ks * 1536 + l * 8);
        acc[0] = __builtin_amdgcn_mfma_f32_16x16x32_bf16(a, wp[0],   acc[0], 0, 0, 0);
        acc[1] = __builtin_amdgcn_mfma_f32_16x16x32_bf16(a, wp[64],  acc[1], 0, 0, 0);
        acc[2] = __builtin_amdgcn_mfma_f32_16x16x32_bf16(a, wp[128], acc[2], 0, 0, 0);
    }

    #pragma unroll
    for (int nf = 0; nf < 3; ++nf) {
        int n = nf * 16 + lr;
        float bias = bq[n];
        int t  = n / 3;
        int kk = n - t * 3;
        #pragma unroll
        for (int r = 0; r < 4; ++r) {
            int row = row0 + lk * 4 + r;
            int b   = row >> 10;
            int h   = (row >> 6) & 15;
            int sp  = row & 63;
            int dg  = sp * 2 + (t >> 3);
            int j   = t & 7;
            wgtA[(((size_t)(b * 3 + kk) * 128 + dg) << 7) + h * 8 + j] = f2bf(acc[nf][r] + bias);
        }
    }
}

// ---------------------------------------------------------------------------
// Kernel B v10 (champion, 60.2 total): global_load_lds staging + counted
// inline vmcnt. Grid 1024 (32 b x 32 st), 256 thr, 4 waves: ss=w&1 (s-sub
// 16), dh=w>>1 (d-half 512). 16 steps x 32 d per half. Keys staged as f32,
// QUAD-buffered (4 x 36 rows x 256B): 3 stage batches in flight, issued
// BEFORE the wait. Wave 0 stages (9 global_load_lds dwordx4 / step). LDS
// swizzle via inverse-XOR'd global source + XOR'd read. f32->bf16 at
// frag-build. Raw s_barrier in loop. Output stores NON-TEMPORAL (2 MB,
// no reuse -> keep out of L3).
// ---------------------------------------------------------------------------
__global__ __launch_bounds__(256, 4) void conv_mfma(const float* __restrict__ Key,
                                                    const short* __restrict__ wgtA,
                                                    float* __restrict__ out) {
    __shared__ char stage[4 * 9216];      // 36864 B
    __shared__ float red[2][16][17];      //  2176 B
    const int blk = (blockIdx.x & 7) * 128 + (blockIdx.x >> 3);  // XCD swizzle
    const int st  = blk & 31;
    const int b   = blk >> 5;
    const int tid = threadIdx.x;
    const int l   = tid & 63;
    const int w   = tid >> 6;
    const int lr  = l & 15;
    const int lk  = l >> 4;
    const int ss  = w & 1;
    const int dh  = w >> 1;
    const int s0  = st << 5;

    // per-lane staging sources (used by wave 0): instruction i covers rows
    // 4i..4i+3; lane l -> row 4i+(l>>4), LDS slot byte (l&15)*16 within the
    // 256B row. Source byte = slot ^ ((row&7)<<4)  [inverse swizzle], then
    // mapped: byte<128 -> d-half 0, >=128 -> half 1
    const char* gaddr[9];
    {
        const char* keyB = (const char*)(Key + ((size_t)b << 20));
        int cb = (l & 15) << 4;
        #pragma unroll
        for (int i = 0; i < 9; ++i) {
            int grow = i * 4 + (l >> 4);           // 0..35
            int srow = s0 - 1 + grow;
            srow = srow < 0 ? 0 : (srow > 1023 ? 1023 : srow);
            int gb   = cb ^ ((grow & 7) << 4);
            int colb = gb + ((gb >> 7) * 1920);    // gb>=128: 2048+(gb-128)
            gaddr[i] = keyB + (size_t)srow * 4096 + colb;
        }
    }

    const short* wgtW = wgtA + (((size_t)b * 384 + (dh << 6) + lk) << 7) + lr * 8;
    bf16x8 aw0[3], aw1[3];
    f32x4 acc = (f32x4){0.f, 0.f, 0.f, 0.f};

    #define ALOADV(arr, tt) do{ _Pragma("unroll") \
        for (int k3 = 0; k3 < 3; ++k3) \
            arr[k3] = *(const bf16x8*)(wgtW + k3 * 16384 + (tt) * 512); }while(0)

    #define STAGEV(tt) do{ char* bb_ = stage + ((tt) & 3) * 9216; _Pragma("unroll") \
        for (int i9 = 0; i9 < 9; ++i9) GLDS(gaddr[i9] + (tt) * 128, bb_ + i9 * 1024); }while(0)

    #define ZFIX(tt) do{ \
        if (st == 0  && l < 16) *(f32x4*)(stage + ((tt)&3)*9216 + (l<<4)) = (f32x4){0.f,0.f,0.f,0.f}; \
        if (st == 31 && l < 16) *(f32x4*)(stage + ((tt)&3)*9216 + 33*256 + (l<<4)) = (f32x4){0.f,0.f,0.f,0.f}; \
        if (st == 0 || st == 31) asm volatile("s_waitcnt lgkmcnt(0)" ::: "memory"); }while(0)

    #define COMP(tt) do{ \
        const char* bb_ = stage + ((tt) & 3) * 9216; \
        _Pragma("unroll") for (int k3 = 0; k3 < 3; ++k3) { \
            int row_ = ss * 16 + lr + k3; \
            const char* rb_ = bb_ + row_ * 256; \
            int sw_ = (row_ & 7) << 4; \
            int x_  = (dh << 7) + (lk << 5); \
            f32x4 v0_ = *(const f32x4*)(rb_ + ((x_) ^ sw_)); \
            f32x4 v1_ = *(const f32x4*)(rb_ + ((x_ + 16) ^ sw_)); \
            bf16x8 a_ = ((tt) & 1) ? aw1[k3] : aw0[k3]; \
            acc = __builtin_amdgcn_mfma_f32_16x16x32_bf16(a_, pack8(v0_, v1_), acc, 0, 0, 0); \
        } }while(0)

    // step: [A(t+1)] [S(t+3)] [counted vmcnt] [barrier] [compute] [barrier]
    #define STEP(tt, NW0, NWX) do{ \
        if ((tt) < 15) { if ((tt) & 1) ALOADV(aw0, (tt)+1); else ALOADV(aw1, (tt)+1); } \
        if (w == 0) { \
            if ((tt) < 13) STAGEV((tt) + 3); \
            asm volatile("s_waitcnt vmcnt(" NW0 ")" ::: "memory"); \
            ZFIX(tt); \
        } else { \
            asm volatile("s_waitcnt vmcnt(" NWX ")" ::: "memory"); \
        } \
        __builtin_amdgcn_s_barrier(); \
        asm volatile("" ::: "memory"); \
        COMP(tt); \
        asm volatile("" ::: "memory"); \
        __builtin_amdgcn_s_barrier(); }while(0)

    // prologue: 3 stage batches in flight + A(0)
    if (w == 0) { STAGEV(0); STAGEV(1); STAGEV(2); }
    ALOADV(aw0, 0);

    STEP(0,  "21", "3");  STEP(1,  "21", "3");  STEP(2,  "21", "3");
    STEP(3,  "21", "3");  STEP(4,  "21", "3");  STEP(5,  "21", "3");
    STEP(6,  "21", "3");  STEP(7,  "21", "3");  STEP(8,  "21", "3");
    STEP(9,  "21", "3");  STEP(10, "21", "3");  STEP(11, "21", "3");
    STEP(12, "21", "3");  STEP(13, "12", "3");  STEP(14, "3",  "3");
    STEP(15, "0",  "0");

    #undef ALOADV
    #undef STAGEV
    #undef ZFIX
    #undef COMP
    #undef STEP

    // combine d-halves
    if (dh == 1) {
        #pragma unroll
        for (int r4 = 0; r4 < 4; ++r4) red[ss][lk * 4 + r4][lr] = acc[r4];
    }
    __syncthreads();
    if (dh == 0) {
        const int s = s0 + ss * 16 + lr;
        #pragma unroll
        for (int r4 = 0; r4 < 4; ++r4) {
            int h = lk * 4 + r4;
            __builtin_nontemporal_store(acc[r4] + red[ss][h][lr],
                                        &out[(((b << 4) + h) << 10) + s]);
        }
    }
}

extern "C" void kernel_launch(void* const* d_in, const int* in_sizes, int n_in,
                              void* d_out, int out_size, void* d_ws, size_t ws_size,
                              hipStream_t stream) {
    const float* Q  = (const float*)d_in[0];
    const float* K  = (const float*)d_in[1];
    const float* Wq = (const float*)d_in[4];
    const float* bq = (const float*)d_in[5];
    float* outp = (float*)d_out;

    short* wfrag = (short*)d_ws;                      // 98304 B
    short* wgtA  = (short*)((char*)d_ws + 98304);     // 3145728 B

    hipLaunchKernelGGL(prep_wfrag, dim3(192),  dim3(256), 0, stream, Wq, wfrag);
    hipLaunchKernelGGL(qk_gemm,    dim3(512),  dim3(256), 0, stream, Q, wfrag, bq, wgtA);
    hipLaunchKernelGGL(conv_mfma,  dim3(1024), dim3(256), 0, stream, K, wgtA, outp);
}